// Round 14
// baseline (770.638 us; speedup 1.0000x reference)
//
#include <hip/hip_runtime.h>
#include <cmath>

#define MN 20000
#define DM 512
#define NE 640000
#define CAP 128   // LDS slot offsets per node (deg>CAP handled by scalar fallback)
#define NT 20     // source tiles (1024 src nodes -> ~2MB k/v window)
#define TSHIFT 10

typedef short  bf16x8 __attribute__((ext_vector_type(8)));
typedef float  f32x4  __attribute__((ext_vector_type(4)));

// RNE fp32 -> bf16 (inputs finite)
__device__ __forceinline__ ushort f2b(float x) {
    unsigned u = __builtin_bit_cast(unsigned, x);
    u += 0x7FFF + ((u >> 16) & 1);
    return (ushort)(u >> 16);
}
__device__ __forceinline__ float b2f(ushort b) {
    return __builtin_bit_cast(float, (unsigned)b << 16);
}

// ===================== fused conversion + edge histograms ===================
#define NS4   (MN * DM / 4)
#define NWC4  (1536 * 512 / 4)
#define NWO4  (512 * 512 / 4)
#define NB4   (1536 / 4)

__device__ __forceinline__ const float* wc_src_row(int r, const float* Wq, const float* Wkv) {
    if (r < 512) return Wq + ((size_t)r << 9);
    if (r < 1024) { int h = (r - 512) >> 6, j = (r - 512) & 63;  return Wkv + ((size_t)(h * 128 + j) << 9); }
    { int h = (r - 1024) >> 6, j = (r - 1024) & 63; return Wkv + ((size_t)(h * 128 + 64 + j) << 9); }
}

__global__ void conv_all_k(const float* __restrict__ s, const float* __restrict__ Wq,
                           const float* __restrict__ Wkv, const float* __restrict__ Wo,
                           const float* __restrict__ bq, const float* __restrict__ bkv,
                           const int* __restrict__ esrc, const int* __restrict__ etgt,
                           int* __restrict__ counts, int* __restrict__ counts2,
                           ushort* __restrict__ s_b, ushort* __restrict__ Wc_b,
                           ushort* __restrict__ Wo_b, float* __restrict__ bc)
{
    int i = blockIdx.x * blockDim.x + threadIdx.x;
    if (i < NE) {                                   // fused edge count + tile histogram
        int t = etgt[i];
        atomicAdd(&counts[t], 1);
        atomicAdd(&counts2[t * NT + (esrc[i] >> TSHIFT)], 1);
    }
    if (i < NS4) {
        float4 v = ((const float4*)s)[i];
        ushort4 o = { f2b(v.x), f2b(v.y), f2b(v.z), f2b(v.w) };
        ((ushort4*)s_b)[i] = o;
        return;
    }
    i -= NS4;
    if (i < NWC4) {
        int e = i * 4, row = e >> 9, col = e & 511;
        float4 v = *(const float4*)(wc_src_row(row, Wq, Wkv) + col);
        ushort4 o = { f2b(v.x), f2b(v.y), f2b(v.z), f2b(v.w) };
        ((ushort4*)Wc_b)[i] = o;
        return;
    }
    i -= NWC4;
    if (i < NWO4) {
        float4 v = ((const float4*)Wo)[i];
        ushort4 o = { f2b(v.x), f2b(v.y), f2b(v.z), f2b(v.w) };
        ((ushort4*)Wo_b)[i] = o;
        return;
    }
    i -= NWO4;
    if (i < NB4) {
#pragma unroll
        for (int u = 0; u < 4; ++u) {
            int r = i * 4 + u;
            float v;
            if (r < 512) v = bq[r];
            else if (r < 1024) { int h = (r - 512) >> 6, j = (r - 512) & 63;  v = bkv[h * 128 + j]; }
            else               { int h = (r - 1024) >> 6, j = (r - 1024) & 63; v = bkv[h * 128 + 64 + j]; }
            bc[r] = v;
        }
    }
}

// ===================== MFMA GEMM: C = A @ B^T + bias ========================
// 256x256 tile, BK=64, 512 threads (8 waves as 2x4, wave tile 128x64).
// Staging bytes/output halve vs 128^2 (8B vs 16B) and block count drops 4x
// (fewer barrier-drain episodes). LDS 2x32KB, 128B rows swizzled
// byte^=(row&7)<<4, matched write (pre-swizzled global src) / ds_read.
// 1D grid, bijective XCD chunking (m204) + column-fastest decode.
template<bool OUTBF>
__global__ __launch_bounds__(512) void gemm_mfma(
    const ushort* __restrict__ Ah, const ushort* __restrict__ Bh,
    const float* __restrict__ bias, void* __restrict__ Cout,
    int M, int N, int K, int NCB)
{
    __shared__ ushort lds[2 * 16384];   // A tile 256x64 bf16 (32KB) + B tile
    const int nwg = gridDim.x;
    const int o = blockIdx.x;
    const int q8 = nwg >> 3, r8 = nwg & 7, x = o & 7, sl = o >> 3;
    const int wg = (x < r8 ? x * (q8 + 1) : r8 * (q8 + 1) + (x - r8) * q8) + sl;
    const int row0 = (wg / NCB) * 256, col0 = (wg % NCB) * 256;

    const int tid = threadIdx.x;
    const int wid = tid >> 6, l = tid & 63;
    const int wm = (wid >> 2) * 128;   // wave row (2 rows of waves)
    const int wn = (wid & 3) * 64;     // wave col (4 cols of waves)
    const int fr = l & 15, g = l >> 4;
    const int fcb = g << 4;            // byte col of fragment within 64B k-half

    f32x4 acc[8][4] = {};

    for (int k0 = 0; k0 < K; k0 += 64) {
        __syncthreads();
#pragma unroll
        for (int p = 0; p < 4; ++p) {
            const int lb  = p * 8192 + tid * 16;            // byte in 32KB tile
            const int r   = lb >> 7;                        // tile row (128B rows)
            const int cbs = (lb & 127) ^ ((r & 7) << 4);    // swizzled source col
            const int ar  = min(row0 + r, M - 1);
            const int br  = col0 + r;                       // N multiple of 256
            const size_t aoff = (size_t)ar * K + k0 + (cbs >> 1);
            const size_t boff = (size_t)br * K + k0 + (cbs >> 1);
            __builtin_amdgcn_global_load_lds(
                (const __attribute__((address_space(1))) void*)(Ah + aoff),
                (__attribute__((address_space(3))) void*)&lds[0 * 16384 + (lb >> 1)], 16, 0, 0);
            __builtin_amdgcn_global_load_lds(
                (const __attribute__((address_space(1))) void*)(Bh + boff),
                (__attribute__((address_space(3))) void*)&lds[1 * 16384 + (lb >> 1)], 16, 0, 0);
        }
        __syncthreads();

#pragma unroll
        for (int kk = 0; kk < 2; ++kk) {
            bf16x8 a[8], b[4];
#pragma unroll
            for (int m = 0; m < 8; ++m) {
                const int r  = wm + m * 16 + fr;
                const int cb = (kk * 64 + fcb) ^ ((r & 7) << 4);
                a[m] = *(const bf16x8*)&lds[0 * 16384 + r * 64 + (cb >> 1)];
            }
#pragma unroll
            for (int n = 0; n < 4; ++n) {
                const int r  = wn + n * 16 + fr;
                const int cb = (kk * 64 + fcb) ^ ((r & 7) << 4);
                b[n] = *(const bf16x8*)&lds[1 * 16384 + r * 64 + (cb >> 1)];
            }
#pragma unroll
            for (int m = 0; m < 8; ++m)
#pragma unroll
                for (int n = 0; n < 4; ++n)
                    acc[m][n] = __builtin_amdgcn_mfma_f32_16x16x32_bf16(a[m], b[n], acc[m][n], 0, 0, 0);
        }
    }

    // epilogue: C/D layout col=lane&15, row=(lane>>4)*4+reg  [m89/m91]
#pragma unroll
    for (int n = 0; n < 4; ++n) {
        const int cg = col0 + wn + n * 16 + fr;
        const float bv = bias[cg];
#pragma unroll
        for (int m = 0; m < 8; ++m) {
#pragma unroll
            for (int j = 0; j < 4; ++j) {
                const int rg = row0 + wm + m * 16 + g * 4 + j;
                if (rg < M) {
                    const float v = acc[m][n][j] + bv;
                    if (OUTBF) ((ushort*)Cout)[(size_t)rg * N + cg] = f2b(v);
                    else       ((float*)Cout)[(size_t)rg * N + cg] = v;
                }
            }
        }
    }
}

// ===================== CSR build ============================================
// single-block: exclusive scan counts->indptr + degree-bucket hist+scan->dbase
// + per-node NT-tile exclusive scan -> cursor2 (fused former tileoff_k).
__global__ __launch_bounds__(1024) void scan_counts_k(
    const int* __restrict__ counts, int* __restrict__ indptr,
    int* __restrict__ dbase, const int* __restrict__ counts2,
    int* __restrict__ cursor2, int M)
{
    __shared__ int part[1024];
    __shared__ int hist[128];
    const int t  = threadIdx.x;
    if (t < 128) hist[t] = 0;
    __syncthreads();
    const int CH = (M + 1023) / 1024;
    const int base = t * CH;
    int sum = 0;
    for (int i = 0; i < CH; ++i) {
        int idx = base + i;
        if (idx < M) {
            int c = counts[idx];
            sum += c;
            atomicAdd(&hist[127 - min(c, 127)], 1);
        }
    }
    part[t] = sum;
    __syncthreads();
    for (int off = 1; off < 1024; off <<= 1) {
        int v = (t >= off) ? part[t - off] : 0;
        __syncthreads();
        part[t] += v;
        __syncthreads();
    }
    int excl = part[t] - sum;
    for (int i = 0; i < CH; ++i) {
        int idx = base + i;
        if (idx < M) { indptr[idx] = excl; excl += counts[idx]; }
    }
    if (t == 1023) indptr[M] = part[1023];
    if (t == 0) {
        int run = 0;
        for (int b = 0; b < 128; ++b) { int v = hist[b]; dbase[b] = run; run += v; }
    }
    __syncthreads();   // indptr visible block-wide (same CU; barrier fences)
    // fused tileoff: per-node exclusive scan of NT tile counts
    for (int n = t; n < M; n += 1024) {
        int run = indptr[n];
#pragma unroll
        for (int j = 0; j < NT; ++j) {
            cursor2[n * NT + j] = run;
            run += counts2[n * NT + j];
        }
    }
}

// fused: edge scatter (tile-sorted byte offsets) + degree-sorted perm scatter
__global__ void scatter_fused_k(const int* __restrict__ src, const int* __restrict__ tgt,
                                int* __restrict__ cursor2, int* __restrict__ slot_off,
                                const int* __restrict__ counts, const int* __restrict__ dbase,
                                int* __restrict__ dcur, int* __restrict__ perm, int E, int M)
{
    int e = blockIdx.x * blockDim.x + threadIdx.x;
    if (e < E) {
        int t = tgt[e], s = src[e];
        int pos = atomicAdd(&cursor2[t * NT + (s >> TSHIFT)], 1);
        slot_off[pos] = s * 3072;
    }
    if (e < M) {
        int b = 127 - min(counts[e], 127);
        int pos = atomicAdd(&dcur[b], 1);
        perm[dbase[b] + pos] = e;
    }
}

// ===================== attention: r6 loop + tile-sorted slot lists ==========
// Model (r6-r13): time = lines x avg_latency / (per-CU MSHR queue x 256CU).
// Tile-sorted sweep cut latency 15%; window size beyond that is drift-limited
// -> parked at ~141us / 497MB FETCH.
__global__ __launch_bounds__(256, 4) void attn11_k(
    const ushort* __restrict__ qkv, const int* __restrict__ indptr,
    const int* __restrict__ slot_off, const int* __restrict__ perm,
    ushort* __restrict__ obh)
{
    __shared__ int slots[4][CAP];
    const int w = threadIdx.x >> 6;
    const int l = threadIdx.x & 63;
    const int node = perm[blockIdx.x * 4 + w];
    const int beg = indptr[node], end = indptr[node + 1];
    const int d = end - beg;
    const int dc = min(d, CAP);

    for (int i = l; i < dc; i += 64) slots[w][i] = slot_off[beg + i];
    __syncthreads();

    const char* base = (const char*)qkv + (l << 4);

    float qf[8];
    {
        bf16x8 qv = *(const bf16x8*)(base + (size_t)node * 3072);
#pragma unroll
        for (int j = 0; j < 8; ++j) qf[j] = b2f((ushort)qv[j]);
    }

    float acc[8] = {};
    float ssum = 0.f;

    int i = 0;
    for (; i + 8 <= dc; i += 8) {
        const int4 sa = *(const int4*)&slots[w][i];
        const int4 sb = *(const int4*)&slots[w][i + 4];
        const char* bp[8] = { base + sa.x, base + sa.y, base + sa.z, base + sa.w,
                              base + sb.x, base + sb.y, base + sb.z, base + sb.w };
        bf16x8 kk[8], vv[8];
#pragma unroll
        for (int u = 0; u < 8; ++u) {
            kk[u] = *(const bf16x8*)(bp[u] + 1024);
            vv[u] = *(const bf16x8*)(bp[u] + 2048);
        }
        float p[8];
#pragma unroll
        for (int u = 0; u < 8; ++u) {
            float pu = 0.f;
#pragma unroll
            for (int j = 0; j < 8; ++j) pu = fmaf(qf[j], b2f((ushort)kk[u][j]), pu);
            p[u] = pu;
        }
#pragma unroll
        for (int u = 0; u < 8; ++u) p[u] += __shfl_xor(p[u], 1);
#pragma unroll
        for (int u = 0; u < 8; ++u) p[u] += __shfl_xor(p[u], 2);
#pragma unroll
        for (int u = 0; u < 8; ++u) p[u] += __shfl_xor(p[u], 4);
        float wt[8];
#pragma unroll
        for (int u = 0; u < 8; ++u) { wt[u] = __expf(p[u] * 0.125f); ssum += wt[u]; }
#pragma unroll
        for (int u = 0; u < 8; ++u)
#pragma unroll
            for (int j = 0; j < 8; ++j) acc[j] = fmaf(wt[u], b2f((ushort)vv[u][j]), acc[j]);
    }
    // tail: remainder of cached region + (astronomically rare) deg>CAP spill
    for (; i < d; ++i) {
        const int so = (i < CAP) ? slots[w][i] : slot_off[beg + i];
        const char* b0 = base + so;
        bf16x8 k0 = *(const bf16x8*)(b0 + 1024);
        bf16x8 v0 = *(const bf16x8*)(b0 + 2048);
        float p0 = 0.f;
#pragma unroll
        for (int j = 0; j < 8; ++j) p0 = fmaf(qf[j], b2f((ushort)k0[j]), p0);
        p0 += __shfl_xor(p0, 1); p0 += __shfl_xor(p0, 2); p0 += __shfl_xor(p0, 4);
        const float w0 = __expf(p0 * 0.125f);
        ssum += w0;
#pragma unroll
        for (int j = 0; j < 8; ++j) acc[j] = fmaf(w0, b2f((ushort)v0[j]), acc[j]);
    }

    // epilogue: normalize + bf16 store
    const float inv = (d > 0) ? 1.f / ssum : 0.f;
    ushort4 ph0, ph1;
    ph0.x = f2b(acc[0] * inv); ph0.y = f2b(acc[1] * inv);
    ph0.z = f2b(acc[2] * inv); ph0.w = f2b(acc[3] * inv);
    ph1.x = f2b(acc[4] * inv); ph1.y = f2b(acc[5] * inv);
    ph1.z = f2b(acc[6] * inv); ph1.w = f2b(acc[7] * inv);
    const size_t ob_off = (size_t)node * 512 + (l << 3);
    *(ushort4*)(obh + ob_off)     = ph0;
    *(ushort4*)(obh + ob_off + 4) = ph1;
}

// ===================== launch ===============================================
extern "C" void kernel_launch(void* const* d_in, const int* in_sizes, int n_in,
                              void* d_out, int out_size, void* d_ws, size_t ws_size,
                              hipStream_t stream)
{
    const float* s   = (const float*)d_in[0];
    const int*   eix = (const int*)d_in[1];   // [2, E]: row0 = src, row1 = tgt
    const float* Wq  = (const float*)d_in[2];
    const float* bq  = (const float*)d_in[3];
    const float* Wkv = (const float*)d_in[4];
    const float* bkv = (const float*)d_in[5];
    const float* Wo  = (const float*)d_in[6];
    const float* bo  = (const float*)d_in[7];
    float* out = (float*)d_out;

    char* ws = (char*)d_ws;
    auto take = [&](size_t bytes) { char* p = ws; ws += (bytes + 255) & ~(size_t)255; return p; };
    ushort* qkv_b  = (ushort*)take((size_t)MN * 1536 * 2);
    ushort* s_b    = (ushort*)take((size_t)MN * 512 * 2);
    ushort* obh    = (ushort*)take((size_t)MN * 512 * 2);
    ushort* Wc_b   = (ushort*)take((size_t)1536 * 512 * 2);
    ushort* Wo_b   = (ushort*)take((size_t)512 * 512 * 2);
    float*  bc     = (float*)take(1536 * 4);
    // contiguous zero-init region: counts | dcur | counts2  (one memset)
    int* counts    = (int*)take(((size_t)MN + 128 + (size_t)MN * NT) * 4);
    int* dcur      = counts + MN;
    int* counts2   = dcur + 128;
    int* cursor2   = (int*)take((size_t)MN * NT * 4);
    int* slot_off  = (int*)take((size_t)NE * 4);
    int* indptr    = (int*)take((MN + 4) * 4);
    int* dbase     = (int*)take(128 * 4);
    int* perm      = (int*)take(MN * 4);

    hipMemsetAsync(counts, 0, ((size_t)MN + 128 + (size_t)MN * NT) * 4, stream);

    // fused conversions / permutations / edge histograms
    const int convN = NS4 + NWC4 + NWO4 + NB4;
    conv_all_k<<<(convN + 255) / 256, 256, 0, stream>>>(s, Wq, Wkv, Wo, bq, bkv,
                                                        eix, eix + NE, counts, counts2,
                                                        s_b, Wc_b, Wo_b, bc);

    // CSR by target (tile-sorted lists) + degree sort; tileoff fused into scan
    scan_counts_k<<<1, 1024, 0, stream>>>(counts, indptr, dbase, counts2, cursor2, MN);
    scatter_fused_k<<<NE / 256, 256, 0, stream>>>(eix, eix + NE, cursor2, slot_off,
                                                  counts, dbase, dcur, perm, NE, MN);

    // QKV projection: qkv_b = s_b @ Wc_b^T + bc  (bf16 out, cols q|k|v)
    const int g1 = ((MN + 255) / 256) * (1536 / 256);   // 79 x 6 = 474
    gemm_mfma<true><<<g1, 512, 0, stream>>>(s_b, Wc_b, bc, qkv_b,
                                            MN, 1536, DM, 1536 / 256);

    // attention: one wave per node (degree-sorted), tile-sorted gathers
    attn11_k<<<MN / 4, 256, 0, stream>>>(qkv_b, indptr, slot_off, perm, obh);

    // output projection (bf16 MFMA): out = ob @ Wo^T + bo, fp32 out
    const int g2 = ((MN + 255) / 256) * (512 / 256);    // 79 x 2 = 158
    gemm_mfma<false><<<g2, 512, 0, stream>>>(obh, Wo_b, bo, out,
                                             MN, 512, DM, 512 / 256);
}

// Round 15
// 402.020 us; speedup vs baseline: 1.9169x; 1.9169x over previous
//
#include <hip/hip_runtime.h>
#include <cmath>

#define MN 20000
#define DM 512
#define NE 640000
#define CAP 128   // LDS slot offsets per node (deg>CAP handled by scalar fallback)
#define NT 20     // source tiles (1024 src nodes -> ~2MB k/v window)
#define TSHIFT 10

typedef short  bf16x8 __attribute__((ext_vector_type(8)));
typedef float  f32x4  __attribute__((ext_vector_type(4)));

// RNE fp32 -> bf16 (inputs finite)
__device__ __forceinline__ ushort f2b(float x) {
    unsigned u = __builtin_bit_cast(unsigned, x);
    u += 0x7FFF + ((u >> 16) & 1);
    return (ushort)(u >> 16);
}
__device__ __forceinline__ float b2f(ushort b) {
    return __builtin_bit_cast(float, (unsigned)b << 16);
}

// ===================== fused conversion + edge histograms ===================
#define NS4   (MN * DM / 4)
#define NWC4  (1536 * 512 / 4)
#define NWO4  (512 * 512 / 4)
#define NB4   (1536 / 4)

__device__ __forceinline__ const float* wc_src_row(int r, const float* Wq, const float* Wkv) {
    if (r < 512) return Wq + ((size_t)r << 9);
    if (r < 1024) { int h = (r - 512) >> 6, j = (r - 512) & 63;  return Wkv + ((size_t)(h * 128 + j) << 9); }
    { int h = (r - 1024) >> 6, j = (r - 1024) & 63; return Wkv + ((size_t)(h * 128 + 64 + j) << 9); }
}

__global__ void conv_all_k(const float* __restrict__ s, const float* __restrict__ Wq,
                           const float* __restrict__ Wkv, const float* __restrict__ Wo,
                           const float* __restrict__ bq, const float* __restrict__ bkv,
                           const int* __restrict__ esrc, const int* __restrict__ etgt,
                           int* __restrict__ counts, int* __restrict__ counts2,
                           ushort* __restrict__ s_b, ushort* __restrict__ Wc_b,
                           ushort* __restrict__ Wo_b, float* __restrict__ bc)
{
    int i = blockIdx.x * blockDim.x + threadIdx.x;
    if (i < NE) {                                   // fused edge count + tile histogram
        int t = etgt[i];
        atomicAdd(&counts[t], 1);
        atomicAdd(&counts2[t * NT + (esrc[i] >> TSHIFT)], 1);
    }
    if (i < NS4) {
        float4 v = ((const float4*)s)[i];
        ushort4 o = { f2b(v.x), f2b(v.y), f2b(v.z), f2b(v.w) };
        ((ushort4*)s_b)[i] = o;
        return;
    }
    i -= NS4;
    if (i < NWC4) {
        int e = i * 4, row = e >> 9, col = e & 511;
        float4 v = *(const float4*)(wc_src_row(row, Wq, Wkv) + col);
        ushort4 o = { f2b(v.x), f2b(v.y), f2b(v.z), f2b(v.w) };
        ((ushort4*)Wc_b)[i] = o;
        return;
    }
    i -= NWC4;
    if (i < NWO4) {
        float4 v = ((const float4*)Wo)[i];
        ushort4 o = { f2b(v.x), f2b(v.y), f2b(v.z), f2b(v.w) };
        ((ushort4*)Wo_b)[i] = o;
        return;
    }
    i -= NWO4;
    if (i < NB4) {
#pragma unroll
        for (int u = 0; u < 4; ++u) {
            int r = i * 4 + u;
            float v;
            if (r < 512) v = bq[r];
            else if (r < 1024) { int h = (r - 512) >> 6, j = (r - 512) & 63;  v = bkv[h * 128 + j]; }
            else               { int h = (r - 1024) >> 6, j = (r - 1024) & 63; v = bkv[h * 128 + 64 + j]; }
            bc[r] = v;
        }
    }
}

// ===================== MFMA GEMM: C = A @ B^T + bias ========================
// 256x256 tile, BK=64, 512 threads (8 waves as 2x4, wave tile 128x64).
// LDS 2x32KB, 128B rows swizzled byte^=(row&7)<<4, matched write
// (pre-swizzled global src) / ds_read. Bijective XCD chunking (m204).
template<bool OUTBF>
__global__ __launch_bounds__(512) void gemm_mfma(
    const ushort* __restrict__ Ah, const ushort* __restrict__ Bh,
    const float* __restrict__ bias, void* __restrict__ Cout,
    int M, int N, int K, int NCB)
{
    __shared__ ushort lds[2 * 16384];   // A tile 256x64 bf16 (32KB) + B tile
    const int nwg = gridDim.x;
    const int o = blockIdx.x;
    const int q8 = nwg >> 3, r8 = nwg & 7, x = o & 7, sl = o >> 3;
    const int wg = (x < r8 ? x * (q8 + 1) : r8 * (q8 + 1) + (x - r8) * q8) + sl;
    const int row0 = (wg / NCB) * 256, col0 = (wg % NCB) * 256;

    const int tid = threadIdx.x;
    const int wid = tid >> 6, l = tid & 63;
    const int wm = (wid >> 2) * 128;   // wave row (2 rows of waves)
    const int wn = (wid & 3) * 64;     // wave col (4 cols of waves)
    const int fr = l & 15, g = l >> 4;
    const int fcb = g << 4;            // byte col of fragment within 64B k-half

    f32x4 acc[8][4] = {};

    for (int k0 = 0; k0 < K; k0 += 64) {
        __syncthreads();
#pragma unroll
        for (int p = 0; p < 4; ++p) {
            const int lb  = p * 8192 + tid * 16;            // byte in 32KB tile
            const int r   = lb >> 7;                        // tile row (128B rows)
            const int cbs = (lb & 127) ^ ((r & 7) << 4);    // swizzled source col
            const int ar  = min(row0 + r, M - 1);
            const int br  = col0 + r;                       // N multiple of 256
            const size_t aoff = (size_t)ar * K + k0 + (cbs >> 1);
            const size_t boff = (size_t)br * K + k0 + (cbs >> 1);
            __builtin_amdgcn_global_load_lds(
                (const __attribute__((address_space(1))) void*)(Ah + aoff),
                (__attribute__((address_space(3))) void*)&lds[0 * 16384 + (lb >> 1)], 16, 0, 0);
            __builtin_amdgcn_global_load_lds(
                (const __attribute__((address_space(1))) void*)(Bh + boff),
                (__attribute__((address_space(3))) void*)&lds[1 * 16384 + (lb >> 1)], 16, 0, 0);
        }
        __syncthreads();

#pragma unroll
        for (int kk = 0; kk < 2; ++kk) {
            bf16x8 a[8], b[4];
#pragma unroll
            for (int m = 0; m < 8; ++m) {
                const int r  = wm + m * 16 + fr;
                const int cb = (kk * 64 + fcb) ^ ((r & 7) << 4);
                a[m] = *(const bf16x8*)&lds[0 * 16384 + r * 64 + (cb >> 1)];
            }
#pragma unroll
            for (int n = 0; n < 4; ++n) {
                const int r  = wn + n * 16 + fr;
                const int cb = (kk * 64 + fcb) ^ ((r & 7) << 4);
                b[n] = *(const bf16x8*)&lds[1 * 16384 + r * 64 + (cb >> 1)];
            }
#pragma unroll
            for (int m = 0; m < 8; ++m)
#pragma unroll
                for (int n = 0; n < 4; ++n)
                    acc[m][n] = __builtin_amdgcn_mfma_f32_16x16x32_bf16(a[m], b[n], acc[m][n], 0, 0, 0);
        }
    }

    // epilogue: C/D layout col=lane&15, row=(lane>>4)*4+reg  [m89/m91]
#pragma unroll
    for (int n = 0; n < 4; ++n) {
        const int cg = col0 + wn + n * 16 + fr;
        const float bv = bias[cg];
#pragma unroll
        for (int m = 0; m < 8; ++m) {
#pragma unroll
            for (int j = 0; j < 4; ++j) {
                const int rg = row0 + wm + m * 16 + g * 4 + j;
                if (rg < M) {
                    const float v = acc[m][n][j] + bv;
                    if (OUTBF) ((ushort*)Cout)[(size_t)rg * N + cg] = f2b(v);
                    else       ((float*)Cout)[(size_t)rg * N + cg] = v;
                }
            }
        }
    }
}

// ===================== CSR build ============================================
// single-block: exclusive scan counts->indptr + degree-bucket hist+scan->dbase
__global__ __launch_bounds__(1024) void scan_counts_k(
    const int* __restrict__ counts, int* __restrict__ indptr,
    int* __restrict__ dbase, int M)
{
    __shared__ int part[1024];
    __shared__ int hist[128];
    const int t  = threadIdx.x;
    if (t < 128) hist[t] = 0;
    __syncthreads();
    const int CH = (M + 1023) / 1024;
    const int base = t * CH;
    int sum = 0;
    for (int i = 0; i < CH; ++i) {
        int idx = base + i;
        if (idx < M) {
            int c = counts[idx];
            sum += c;
            atomicAdd(&hist[127 - min(c, 127)], 1);
        }
    }
    part[t] = sum;
    __syncthreads();
    for (int off = 1; off < 1024; off <<= 1) {
        int v = (t >= off) ? part[t - off] : 0;
        __syncthreads();
        part[t] += v;
        __syncthreads();
    }
    int excl = part[t] - sum;
    for (int i = 0; i < CH; ++i) {
        int idx = base + i;
        if (idx < M) { indptr[idx] = excl; excl += counts[idx]; }
    }
    if (t == 1023) indptr[M] = part[1023];
    if (t == 0) {
        int run = 0;
        for (int b = 0; b < 128; ++b) { int v = hist[b]; dbase[b] = run; run += v; }
    }
}

// per-node: exclusive scan of NT tile counts -> scatter cursors
// (parallel-sized job: 79 blocks; r14 fused this into the 1-block scan and
// paid 412us of single-CU latency-serialized strided traffic)
__global__ void tileoff_k(const int* __restrict__ indptr, const int* __restrict__ counts2,
                          int* __restrict__ cursor2, int M)
{
    int n = blockIdx.x * blockDim.x + threadIdx.x;
    if (n >= M) return;
    int run = indptr[n];
#pragma unroll
    for (int j = 0; j < NT; ++j) {
        cursor2[n * NT + j] = run;
        run += counts2[n * NT + j];
    }
}

// fused: edge scatter (tile-sorted byte offsets) + degree-sorted perm scatter
__global__ void scatter_fused_k(const int* __restrict__ src, const int* __restrict__ tgt,
                                int* __restrict__ cursor2, int* __restrict__ slot_off,
                                const int* __restrict__ counts, const int* __restrict__ dbase,
                                int* __restrict__ dcur, int* __restrict__ perm, int E, int M)
{
    int e = blockIdx.x * blockDim.x + threadIdx.x;
    if (e < E) {
        int t = tgt[e], s = src[e];
        int pos = atomicAdd(&cursor2[t * NT + (s >> TSHIFT)], 1);
        slot_off[pos] = s * 3072;
    }
    if (e < M) {
        int b = 127 - min(counts[e], 127);
        int pos = atomicAdd(&dcur[b], 1);
        perm[dbase[b] + pos] = e;
    }
}

// ===================== attention: r6 loop + tile-sorted slot lists ==========
// Model (r6-r13): time = lines x avg_latency / (per-CU MSHR queue x 256CU).
// Tile-sorted sweep cut latency 15%; window size beyond that is drift-limited
// -> parked at ~141us / 497MB FETCH.
__global__ __launch_bounds__(256, 4) void attn11_k(
    const ushort* __restrict__ qkv, const int* __restrict__ indptr,
    const int* __restrict__ slot_off, const int* __restrict__ perm,
    ushort* __restrict__ obh)
{
    __shared__ int slots[4][CAP];
    const int w = threadIdx.x >> 6;
    const int l = threadIdx.x & 63;
    const int node = perm[blockIdx.x * 4 + w];
    const int beg = indptr[node], end = indptr[node + 1];
    const int d = end - beg;
    const int dc = min(d, CAP);

    for (int i = l; i < dc; i += 64) slots[w][i] = slot_off[beg + i];
    __syncthreads();

    const char* base = (const char*)qkv + (l << 4);

    float qf[8];
    {
        bf16x8 qv = *(const bf16x8*)(base + (size_t)node * 3072);
#pragma unroll
        for (int j = 0; j < 8; ++j) qf[j] = b2f((ushort)qv[j]);
    }

    float acc[8] = {};
    float ssum = 0.f;

    int i = 0;
    for (; i + 8 <= dc; i += 8) {
        const int4 sa = *(const int4*)&slots[w][i];
        const int4 sb = *(const int4*)&slots[w][i + 4];
        const char* bp[8] = { base + sa.x, base + sa.y, base + sa.z, base + sa.w,
                              base + sb.x, base + sb.y, base + sb.z, base + sb.w };
        bf16x8 kk[8], vv[8];
#pragma unroll
        for (int u = 0; u < 8; ++u) {
            kk[u] = *(const bf16x8*)(bp[u] + 1024);
            vv[u] = *(const bf16x8*)(bp[u] + 2048);
        }
        float p[8];
#pragma unroll
        for (int u = 0; u < 8; ++u) {
            float pu = 0.f;
#pragma unroll
            for (int j = 0; j < 8; ++j) pu = fmaf(qf[j], b2f((ushort)kk[u][j]), pu);
            p[u] = pu;
        }
#pragma unroll
        for (int u = 0; u < 8; ++u) p[u] += __shfl_xor(p[u], 1);
#pragma unroll
        for (int u = 0; u < 8; ++u) p[u] += __shfl_xor(p[u], 2);
#pragma unroll
        for (int u = 0; u < 8; ++u) p[u] += __shfl_xor(p[u], 4);
        float wt[8];
#pragma unroll
        for (int u = 0; u < 8; ++u) { wt[u] = __expf(p[u] * 0.125f); ssum += wt[u]; }
#pragma unroll
        for (int u = 0; u < 8; ++u)
#pragma unroll
            for (int j = 0; j < 8; ++j) acc[j] = fmaf(wt[u], b2f((ushort)vv[u][j]), acc[j]);
    }
    // tail: remainder of cached region + (astronomically rare) deg>CAP spill
    for (; i < d; ++i) {
        const int so = (i < CAP) ? slots[w][i] : slot_off[beg + i];
        const char* b0 = base + so;
        bf16x8 k0 = *(const bf16x8*)(b0 + 1024);
        bf16x8 v0 = *(const bf16x8*)(b0 + 2048);
        float p0 = 0.f;
#pragma unroll
        for (int j = 0; j < 8; ++j) p0 = fmaf(qf[j], b2f((ushort)k0[j]), p0);
        p0 += __shfl_xor(p0, 1); p0 += __shfl_xor(p0, 2); p0 += __shfl_xor(p0, 4);
        const float w0 = __expf(p0 * 0.125f);
        ssum += w0;
#pragma unroll
        for (int j = 0; j < 8; ++j) acc[j] = fmaf(w0, b2f((ushort)v0[j]), acc[j]);
    }

    // epilogue: normalize + bf16 store
    const float inv = (d > 0) ? 1.f / ssum : 0.f;
    ushort4 ph0, ph1;
    ph0.x = f2b(acc[0] * inv); ph0.y = f2b(acc[1] * inv);
    ph0.z = f2b(acc[2] * inv); ph0.w = f2b(acc[3] * inv);
    ph1.x = f2b(acc[4] * inv); ph1.y = f2b(acc[5] * inv);
    ph1.z = f2b(acc[6] * inv); ph1.w = f2b(acc[7] * inv);
    const size_t ob_off = (size_t)node * 512 + (l << 3);
    *(ushort4*)(obh + ob_off)     = ph0;
    *(ushort4*)(obh + ob_off + 4) = ph1;
}

// ===================== launch ===============================================
extern "C" void kernel_launch(void* const* d_in, const int* in_sizes, int n_in,
                              void* d_out, int out_size, void* d_ws, size_t ws_size,
                              hipStream_t stream)
{
    const float* s   = (const float*)d_in[0];
    const int*   eix = (const int*)d_in[1];   // [2, E]: row0 = src, row1 = tgt
    const float* Wq  = (const float*)d_in[2];
    const float* bq  = (const float*)d_in[3];
    const float* Wkv = (const float*)d_in[4];
    const float* bkv = (const float*)d_in[5];
    const float* Wo  = (const float*)d_in[6];
    const float* bo  = (const float*)d_in[7];
    float* out = (float*)d_out;

    char* ws = (char*)d_ws;
    auto take = [&](size_t bytes) { char* p = ws; ws += (bytes + 255) & ~(size_t)255; return p; };
    ushort* qkv_b  = (ushort*)take((size_t)MN * 1536 * 2);
    ushort* s_b    = (ushort*)take((size_t)MN * 512 * 2);
    ushort* obh    = (ushort*)take((size_t)MN * 512 * 2);
    ushort* Wc_b   = (ushort*)take((size_t)1536 * 512 * 2);
    ushort* Wo_b   = (ushort*)take((size_t)512 * 512 * 2);
    float*  bc     = (float*)take(1536 * 4);
    // contiguous zero-init region: counts | dcur | counts2  (one memset)
    int* counts    = (int*)take(((size_t)MN + 128 + (size_t)MN * NT) * 4);
    int* dcur      = counts + MN;
    int* counts2   = dcur + 128;
    int* cursor2   = (int*)take((size_t)MN * NT * 4);
    int* slot_off  = (int*)take((size_t)NE * 4);
    int* indptr    = (int*)take((MN + 4) * 4);
    int* dbase     = (int*)take(128 * 4);
    int* perm      = (int*)take(MN * 4);

    hipMemsetAsync(counts, 0, ((size_t)MN + 128 + (size_t)MN * NT) * 4, stream);

    // fused conversions / permutations / edge histograms
    const int convN = NS4 + NWC4 + NWO4 + NB4;
    conv_all_k<<<(convN + 255) / 256, 256, 0, stream>>>(s, Wq, Wkv, Wo, bq, bkv,
                                                        eix, eix + NE, counts, counts2,
                                                        s_b, Wc_b, Wo_b, bc);

    // CSR by target (tile-sorted lists) + degree sort
    scan_counts_k<<<1, 1024, 0, stream>>>(counts, indptr, dbase, MN);
    tileoff_k<<<(MN + 255) / 256, 256, 0, stream>>>(indptr, counts2, cursor2, MN);
    scatter_fused_k<<<NE / 256, 256, 0, stream>>>(eix, eix + NE, cursor2, slot_off,
                                                  counts, dbase, dcur, perm, NE, MN);

    // QKV projection: qkv_b = s_b @ Wc_b^T + bc  (bf16 out, cols q|k|v)
    const int g1 = ((MN + 255) / 256) * (1536 / 256);   // 79 x 6 = 474
    gemm_mfma<true><<<g1, 512, 0, stream>>>(s_b, Wc_b, bc, qkv_b,
                                            MN, 1536, DM, 1536 / 256);

    // attention: one wave per node (degree-sorted), tile-sorted gathers
    attn11_k<<<MN / 4, 256, 0, stream>>>(qkv_b, indptr, slot_off, perm, obh);

    // output projection (bf16 MFMA): out = ob @ Wo^T + bo, fp32 out
    const int g2 = ((MN + 255) / 256) * (512 / 256);    // 79 x 2 = 158
    gemm_mfma<false><<<g2, 512, 0, stream>>>(obh, Wo_b, bo, out,
                                             MN, 512, DM, 512 / 256);
}

// Round 16
// 391.009 us; speedup vs baseline: 1.9709x; 1.0282x over previous
//
#include <hip/hip_runtime.h>
#include <cmath>

#define MN 20000
#define DM 512
#define NE 640000
#define CAP 128   // LDS slot offsets per node (deg>CAP handled by scalar fallback)
#define NT 20     // source tiles (1024 src nodes -> ~2MB k/v window)
#define TSHIFT 10

typedef short  bf16x8 __attribute__((ext_vector_type(8)));
typedef float  f32x4  __attribute__((ext_vector_type(4)));

// RNE fp32 -> bf16 (inputs finite)
__device__ __forceinline__ ushort f2b(float x) {
    unsigned u = __builtin_bit_cast(unsigned, x);
    u += 0x7FFF + ((u >> 16) & 1);
    return (ushort)(u >> 16);
}
__device__ __forceinline__ float b2f(ushort b) {
    return __builtin_bit_cast(float, (unsigned)b << 16);
}

// ===================== fused conversion + edge histograms ===================
#define NS4   (MN * DM / 4)
#define NWC4  (1536 * 512 / 4)
#define NWO4  (512 * 512 / 4)
#define NB4   (1536 / 4)

__device__ __forceinline__ const float* wc_src_row(int r, const float* Wq, const float* Wkv) {
    if (r < 512) return Wq + ((size_t)r << 9);
    if (r < 1024) { int h = (r - 512) >> 6, j = (r - 512) & 63;  return Wkv + ((size_t)(h * 128 + j) << 9); }
    { int h = (r - 1024) >> 6, j = (r - 1024) & 63; return Wkv + ((size_t)(h * 128 + 64 + j) << 9); }
}

__global__ void conv_all_k(const float* __restrict__ s, const float* __restrict__ Wq,
                           const float* __restrict__ Wkv, const float* __restrict__ Wo,
                           const float* __restrict__ bq, const float* __restrict__ bkv,
                           const int* __restrict__ esrc, const int* __restrict__ etgt,
                           int* __restrict__ counts, int* __restrict__ counts2,
                           ushort* __restrict__ s_b, ushort* __restrict__ Wc_b,
                           ushort* __restrict__ Wo_b, float* __restrict__ bc)
{
    int i = blockIdx.x * blockDim.x + threadIdx.x;
    if (i < NE) {                                   // fused edge count + tile histogram
        int t = etgt[i];
        atomicAdd(&counts[t], 1);
        atomicAdd(&counts2[t * NT + (esrc[i] >> TSHIFT)], 1);
    }
    if (i < NS4) {
        float4 v = ((const float4*)s)[i];
        ushort4 o = { f2b(v.x), f2b(v.y), f2b(v.z), f2b(v.w) };
        ((ushort4*)s_b)[i] = o;
        return;
    }
    i -= NS4;
    if (i < NWC4) {
        int e = i * 4, row = e >> 9, col = e & 511;
        float4 v = *(const float4*)(wc_src_row(row, Wq, Wkv) + col);
        ushort4 o = { f2b(v.x), f2b(v.y), f2b(v.z), f2b(v.w) };
        ((ushort4*)Wc_b)[i] = o;
        return;
    }
    i -= NWC4;
    if (i < NWO4) {
        float4 v = ((const float4*)Wo)[i];
        ushort4 o = { f2b(v.x), f2b(v.y), f2b(v.z), f2b(v.w) };
        ((ushort4*)Wo_b)[i] = o;
        return;
    }
    i -= NWO4;
    if (i < NB4) {
#pragma unroll
        for (int u = 0; u < 4; ++u) {
            int r = i * 4 + u;
            float v;
            if (r < 512) v = bq[r];
            else if (r < 1024) { int h = (r - 512) >> 6, j = (r - 512) & 63;  v = bkv[h * 128 + j]; }
            else               { int h = (r - 1024) >> 6, j = (r - 1024) & 63; v = bkv[h * 128 + 64 + j]; }
            bc[r] = v;
        }
    }
}

// ===================== MFMA GEMM: C = A @ B^T + bias ========================
// Tile = BM x BM, BK=64, templated:
//   BM=256: 512 threads, 8 waves 2x4, wave tile 128x64 (8B staged/output) —
//           use when grid >= ~2 blocks/CU (GEMM1: 474 blocks).
//   BM=128: 256 threads, 4 waves 2x2, wave tile 64x64 — use for thin N where
//           256^2 would underfill the chip (GEMM2 at 256^2: 158 blocks for
//           256 CUs = 40% idle; r15 regression).
// LDS 128B rows swizzled byte^=(row&7)<<4, matched write (pre-swizzled
// global src; global_load_lds writes linearly) / ds_read. Bijective XCD
// chunking (m204) + column-fastest decode for A-panel L2 locality.
template<int BM, bool OUTBF>
__global__ __launch_bounds__(BM == 256 ? 512 : 256) void gemm_mfma(
    const ushort* __restrict__ Ah, const ushort* __restrict__ Bh,
    const float* __restrict__ bias, void* __restrict__ Cout,
    int M, int N, int K, int NCB)
{
    constexpr int THREADS = (BM == 256) ? 512 : 256;
    constexpr int MR      = (BM == 256) ? 8 : 4;     // 16-row frags per wave
    constexpr int LDSH    = BM * 64;                 // ushorts per tile
    __shared__ ushort lds[2 * LDSH];

    const int nwg = gridDim.x;
    const int o = blockIdx.x;
    const int q8 = nwg >> 3, r8 = nwg & 7, x = o & 7, sl = o >> 3;
    const int wg = (x < r8 ? x * (q8 + 1) : r8 * (q8 + 1) + (x - r8) * q8) + sl;
    const int row0 = (wg / NCB) * BM, col0 = (wg % NCB) * BM;

    const int tid = threadIdx.x;
    const int wid = tid >> 6, l = tid & 63;
    int wm, wn;
    if constexpr (BM == 256) { wm = (wid >> 2) * 128; wn = (wid & 3) * 64; }
    else                     { wm = (wid >> 1) * 64;  wn = (wid & 1) * 64; }
    const int fr = l & 15, g = l >> 4;
    const int fcb = g << 4;            // byte col of fragment within 64B k-half

    f32x4 acc[MR][4] = {};

    for (int k0 = 0; k0 < K; k0 += 64) {
        __syncthreads();
#pragma unroll
        for (int p = 0; p < 4; ++p) {
            const int lb  = p * (THREADS * 16) + tid * 16;  // byte in tile
            const int r   = lb >> 7;                        // tile row (128B rows)
            const int cbs = (lb & 127) ^ ((r & 7) << 4);    // swizzled source col
            const int ar  = min(row0 + r, M - 1);
            const int br  = col0 + r;                       // N multiple of BM
            const size_t aoff = (size_t)ar * K + k0 + (cbs >> 1);
            const size_t boff = (size_t)br * K + k0 + (cbs >> 1);
            __builtin_amdgcn_global_load_lds(
                (const __attribute__((address_space(1))) void*)(Ah + aoff),
                (__attribute__((address_space(3))) void*)&lds[0 * LDSH + (lb >> 1)], 16, 0, 0);
            __builtin_amdgcn_global_load_lds(
                (const __attribute__((address_space(1))) void*)(Bh + boff),
                (__attribute__((address_space(3))) void*)&lds[1 * LDSH + (lb >> 1)], 16, 0, 0);
        }
        __syncthreads();

#pragma unroll
        for (int kk = 0; kk < 2; ++kk) {
            bf16x8 a[MR], b[4];
#pragma unroll
            for (int m = 0; m < MR; ++m) {
                const int r  = wm + m * 16 + fr;
                const int cb = (kk * 64 + fcb) ^ ((r & 7) << 4);
                a[m] = *(const bf16x8*)&lds[0 * LDSH + r * 64 + (cb >> 1)];
            }
#pragma unroll
            for (int n = 0; n < 4; ++n) {
                const int r  = wn + n * 16 + fr;
                const int cb = (kk * 64 + fcb) ^ ((r & 7) << 4);
                b[n] = *(const bf16x8*)&lds[1 * LDSH + r * 64 + (cb >> 1)];
            }
#pragma unroll
            for (int m = 0; m < MR; ++m)
#pragma unroll
                for (int n = 0; n < 4; ++n)
                    acc[m][n] = __builtin_amdgcn_mfma_f32_16x16x32_bf16(a[m], b[n], acc[m][n], 0, 0, 0);
        }
    }

    // epilogue: C/D layout col=lane&15, row=(lane>>4)*4+reg  [m89/m91]
#pragma unroll
    for (int n = 0; n < 4; ++n) {
        const int cg = col0 + wn + n * 16 + fr;
        const float bv = bias[cg];
#pragma unroll
        for (int m = 0; m < MR; ++m) {
#pragma unroll
            for (int j = 0; j < 4; ++j) {
                const int rg = row0 + wm + m * 16 + g * 4 + j;
                if (rg < M) {
                    const float v = acc[m][n][j] + bv;
                    if (OUTBF) ((ushort*)Cout)[(size_t)rg * N + cg] = f2b(v);
                    else       ((float*)Cout)[(size_t)rg * N + cg] = v;
                }
            }
        }
    }
}

// ===================== CSR build ============================================
// single-block: exclusive scan counts->indptr + degree-bucket hist+scan->dbase
__global__ __launch_bounds__(1024) void scan_counts_k(
    const int* __restrict__ counts, int* __restrict__ indptr,
    int* __restrict__ dbase, int M)
{
    __shared__ int part[1024];
    __shared__ int hist[128];
    const int t  = threadIdx.x;
    if (t < 128) hist[t] = 0;
    __syncthreads();
    const int CH = (M + 1023) / 1024;
    const int base = t * CH;
    int sum = 0;
    for (int i = 0; i < CH; ++i) {
        int idx = base + i;
        if (idx < M) {
            int c = counts[idx];
            sum += c;
            atomicAdd(&hist[127 - min(c, 127)], 1);
        }
    }
    part[t] = sum;
    __syncthreads();
    for (int off = 1; off < 1024; off <<= 1) {
        int v = (t >= off) ? part[t - off] : 0;
        __syncthreads();
        part[t] += v;
        __syncthreads();
    }
    int excl = part[t] - sum;
    for (int i = 0; i < CH; ++i) {
        int idx = base + i;
        if (idx < M) { indptr[idx] = excl; excl += counts[idx]; }
    }
    if (t == 1023) indptr[M] = part[1023];
    if (t == 0) {
        int run = 0;
        for (int b = 0; b < 128; ++b) { int v = hist[b]; dbase[b] = run; run += v; }
    }
}

// per-node: exclusive scan of NT tile counts -> scatter cursors
// (parallel-sized: 79 blocks; r14's 1-block fusion of this cost 412us)
__global__ void tileoff_k(const int* __restrict__ indptr, const int* __restrict__ counts2,
                          int* __restrict__ cursor2, int M)
{
    int n = blockIdx.x * blockDim.x + threadIdx.x;
    if (n >= M) return;
    int run = indptr[n];
#pragma unroll
    for (int j = 0; j < NT; ++j) {
        cursor2[n * NT + j] = run;
        run += counts2[n * NT + j];
    }
}

// fused: edge scatter (tile-sorted byte offsets) + degree-sorted perm scatter
__global__ void scatter_fused_k(const int* __restrict__ src, const int* __restrict__ tgt,
                                int* __restrict__ cursor2, int* __restrict__ slot_off,
                                const int* __restrict__ counts, const int* __restrict__ dbase,
                                int* __restrict__ dcur, int* __restrict__ perm, int E, int M)
{
    int e = blockIdx.x * blockDim.x + threadIdx.x;
    if (e < E) {
        int t = tgt[e], s = src[e];
        int pos = atomicAdd(&cursor2[t * NT + (s >> TSHIFT)], 1);
        slot_off[pos] = s * 3072;
    }
    if (e < M) {
        int b = 127 - min(counts[e], 127);
        int pos = atomicAdd(&dcur[b], 1);
        perm[dbase[b] + pos] = e;
    }
}

// ===================== attention: r6 loop + tile-sorted slot lists ==========
// Model (r6-r13): time = lines x avg_latency / (per-CU MSHR queue x 256CU).
// Tile-sorted sweep cut latency 15%; window size beyond that is drift-limited
// -> parked at ~142us / 497MB FETCH.
__global__ __launch_bounds__(256, 4) void attn11_k(
    const ushort* __restrict__ qkv, const int* __restrict__ indptr,
    const int* __restrict__ slot_off, const int* __restrict__ perm,
    ushort* __restrict__ obh)
{
    __shared__ int slots[4][CAP];
    const int w = threadIdx.x >> 6;
    const int l = threadIdx.x & 63;
    const int node = perm[blockIdx.x * 4 + w];
    const int beg = indptr[node], end = indptr[node + 1];
    const int d = end - beg;
    const int dc = min(d, CAP);

    for (int i = l; i < dc; i += 64) slots[w][i] = slot_off[beg + i];
    __syncthreads();

    const char* base = (const char*)qkv + (l << 4);

    float qf[8];
    {
        bf16x8 qv = *(const bf16x8*)(base + (size_t)node * 3072);
#pragma unroll
        for (int j = 0; j < 8; ++j) qf[j] = b2f((ushort)qv[j]);
    }

    float acc[8] = {};
    float ssum = 0.f;

    int i = 0;
    for (; i + 8 <= dc; i += 8) {
        const int4 sa = *(const int4*)&slots[w][i];
        const int4 sb = *(const int4*)&slots[w][i + 4];
        const char* bp[8] = { base + sa.x, base + sa.y, base + sa.z, base + sa.w,
                              base + sb.x, base + sb.y, base + sb.z, base + sb.w };
        bf16x8 kk[8], vv[8];
#pragma unroll
        for (int u = 0; u < 8; ++u) {
            kk[u] = *(const bf16x8*)(bp[u] + 1024);
            vv[u] = *(const bf16x8*)(bp[u] + 2048);
        }
        float p[8];
#pragma unroll
        for (int u = 0; u < 8; ++u) {
            float pu = 0.f;
#pragma unroll
            for (int j = 0; j < 8; ++j) pu = fmaf(qf[j], b2f((ushort)kk[u][j]), pu);
            p[u] = pu;
        }
#pragma unroll
        for (int u = 0; u < 8; ++u) p[u] += __shfl_xor(p[u], 1);
#pragma unroll
        for (int u = 0; u < 8; ++u) p[u] += __shfl_xor(p[u], 2);
#pragma unroll
        for (int u = 0; u < 8; ++u) p[u] += __shfl_xor(p[u], 4);
        float wt[8];
#pragma unroll
        for (int u = 0; u < 8; ++u) { wt[u] = __expf(p[u] * 0.125f); ssum += wt[u]; }
#pragma unroll
        for (int u = 0; u < 8; ++u)
#pragma unroll
            for (int j = 0; j < 8; ++j) acc[j] = fmaf(wt[u], b2f((ushort)vv[u][j]), acc[j]);
    }
    // tail: remainder of cached region + (astronomically rare) deg>CAP spill
    for (; i < d; ++i) {
        const int so = (i < CAP) ? slots[w][i] : slot_off[beg + i];
        const char* b0 = base + so;
        bf16x8 k0 = *(const bf16x8*)(b0 + 1024);
        bf16x8 v0 = *(const bf16x8*)(b0 + 2048);
        float p0 = 0.f;
#pragma unroll
        for (int j = 0; j < 8; ++j) p0 = fmaf(qf[j], b2f((ushort)k0[j]), p0);
        p0 += __shfl_xor(p0, 1); p0 += __shfl_xor(p0, 2); p0 += __shfl_xor(p0, 4);
        const float w0 = __expf(p0 * 0.125f);
        ssum += w0;
#pragma unroll
        for (int j = 0; j < 8; ++j) acc[j] = fmaf(w0, b2f((ushort)v0[j]), acc[j]);
    }

    // epilogue: normalize + bf16 store
    const float inv = (d > 0) ? 1.f / ssum : 0.f;
    ushort4 ph0, ph1;
    ph0.x = f2b(acc[0] * inv); ph0.y = f2b(acc[1] * inv);
    ph0.z = f2b(acc[2] * inv); ph0.w = f2b(acc[3] * inv);
    ph1.x = f2b(acc[4] * inv); ph1.y = f2b(acc[5] * inv);
    ph1.z = f2b(acc[6] * inv); ph1.w = f2b(acc[7] * inv);
    const size_t ob_off = (size_t)node * 512 + (l << 3);
    *(ushort4*)(obh + ob_off)     = ph0;
    *(ushort4*)(obh + ob_off + 4) = ph1;
}

// ===================== launch ===============================================
extern "C" void kernel_launch(void* const* d_in, const int* in_sizes, int n_in,
                              void* d_out, int out_size, void* d_ws, size_t ws_size,
                              hipStream_t stream)
{
    const float* s   = (const float*)d_in[0];
    const int*   eix = (const int*)d_in[1];   // [2, E]: row0 = src, row1 = tgt
    const float* Wq  = (const float*)d_in[2];
    const float* bq  = (const float*)d_in[3];
    const float* Wkv = (const float*)d_in[4];
    const float* bkv = (const float*)d_in[5];
    const float* Wo  = (const float*)d_in[6];
    const float* bo  = (const float*)d_in[7];
    float* out = (float*)d_out;

    char* ws = (char*)d_ws;
    auto take = [&](size_t bytes) { char* p = ws; ws += (bytes + 255) & ~(size_t)255; return p; };
    ushort* qkv_b  = (ushort*)take((size_t)MN * 1536 * 2);
    ushort* s_b    = (ushort*)take((size_t)MN * 512 * 2);
    ushort* obh    = (ushort*)take((size_t)MN * 512 * 2);
    ushort* Wc_b   = (ushort*)take((size_t)1536 * 512 * 2);
    ushort* Wo_b   = (ushort*)take((size_t)512 * 512 * 2);
    float*  bc     = (float*)take(1536 * 4);
    // contiguous zero-init region: counts | dcur | counts2  (one memset)
    int* counts    = (int*)take(((size_t)MN + 128 + (size_t)MN * NT) * 4);
    int* dcur      = counts + MN;
    int* counts2   = dcur + 128;
    int* cursor2   = (int*)take((size_t)MN * NT * 4);
    int* slot_off  = (int*)take((size_t)NE * 4);
    int* indptr    = (int*)take((MN + 4) * 4);
    int* dbase     = (int*)take(128 * 4);
    int* perm      = (int*)take(MN * 4);

    hipMemsetAsync(counts, 0, ((size_t)MN + 128 + (size_t)MN * NT) * 4, stream);

    // fused conversions / permutations / edge histograms
    const int convN = NS4 + NWC4 + NWO4 + NB4;
    conv_all_k<<<(convN + 255) / 256, 256, 0, stream>>>(s, Wq, Wkv, Wo, bq, bkv,
                                                        eix, eix + NE, counts, counts2,
                                                        s_b, Wc_b, Wo_b, bc);

    // CSR by target (tile-sorted lists) + degree sort
    scan_counts_k<<<1, 1024, 0, stream>>>(counts, indptr, dbase, MN);
    tileoff_k<<<(MN + 255) / 256, 256, 0, stream>>>(indptr, counts2, cursor2, MN);
    scatter_fused_k<<<NE / 256, 256, 0, stream>>>(eix, eix + NE, cursor2, slot_off,
                                                  counts, dbase, dcur, perm, NE, MN);

    // QKV projection: 256^2 tile (474 blocks -> ~2/CU, 8B staged/output)
    const int g1 = ((MN + 255) / 256) * (1536 / 256);   // 79 x 6 = 474
    gemm_mfma<256, true><<<g1, 512, 0, stream>>>(s_b, Wc_b, bc, qkv_b,
                                                 MN, 1536, DM, 1536 / 256);

    // attention: one wave per node (degree-sorted), tile-sorted gathers
    attn11_k<<<MN / 4, 256, 0, stream>>>(qkv_b, indptr, slot_off, perm, obh);

    // output projection: 128^2 tile (628 blocks; 256^2 gave only 158 blocks
    // for 256 CUs -> 40% chip idle, the r15 regression)
    const int g2 = ((MN + 127) / 128) * (512 / 128);    // 157 x 4 = 628
    gemm_mfma<128, false><<<g2, 256, 0, stream>>>(obh, Wo_b, bo, out,
                                                  MN, 512, DM, 512 / 128);
}

// Round 17
// 387.099 us; speedup vs baseline: 1.9908x; 1.0101x over previous
//
#include <hip/hip_runtime.h>
#include <cmath>

#define MN 20000
#define DM 512
#define NE 640000
#define CAP 128   // LDS slot offsets per node (deg>CAP handled by scalar fallback)
#define NT 20     // source tiles (1024 src nodes -> ~2MB k/v window)
#define TSHIFT 10

typedef short  bf16x8 __attribute__((ext_vector_type(8)));
typedef float  f32x4  __attribute__((ext_vector_type(4)));

// RNE fp32 -> bf16 (inputs finite)
__device__ __forceinline__ ushort f2b(float x) {
    unsigned u = __builtin_bit_cast(unsigned, x);
    u += 0x7FFF + ((u >> 16) & 1);
    return (ushort)(u >> 16);
}
__device__ __forceinline__ float b2f(ushort b) {
    return __builtin_bit_cast(float, (unsigned)b << 16);
}

// ===================== fused conversion + edge histograms ===================
#define NS4   (MN * DM / 4)
#define NWC4  (1536 * 512 / 4)
#define NWO4  (512 * 512 / 4)
#define NB4   (1536 / 4)

__device__ __forceinline__ const float* wc_src_row(int r, const float* Wq, const float* Wkv) {
    if (r < 512) return Wq + ((size_t)r << 9);
    if (r < 1024) { int h = (r - 512) >> 6, j = (r - 512) & 63;  return Wkv + ((size_t)(h * 128 + j) << 9); }
    { int h = (r - 1024) >> 6, j = (r - 1024) & 63; return Wkv + ((size_t)(h * 128 + 64 + j) << 9); }
}

__global__ void conv_all_k(const float* __restrict__ s, const float* __restrict__ Wq,
                           const float* __restrict__ Wkv, const float* __restrict__ Wo,
                           const float* __restrict__ bq, const float* __restrict__ bkv,
                           const int* __restrict__ esrc, const int* __restrict__ etgt,
                           int* __restrict__ counts, int* __restrict__ counts2,
                           ushort* __restrict__ s_b, ushort* __restrict__ Wc_b,
                           ushort* __restrict__ Wo_b, float* __restrict__ bc)
{
    int i = blockIdx.x * blockDim.x + threadIdx.x;
    if (i < NE) {                                   // fused edge count + tile histogram
        int t = etgt[i];
        atomicAdd(&counts[t], 1);
        atomicAdd(&counts2[t * NT + (esrc[i] >> TSHIFT)], 1);
    }
    if (i < NS4) {
        float4 v = ((const float4*)s)[i];
        ushort4 o = { f2b(v.x), f2b(v.y), f2b(v.z), f2b(v.w) };
        ((ushort4*)s_b)[i] = o;
        return;
    }
    i -= NS4;
    if (i < NWC4) {
        int e = i * 4, row = e >> 9, col = e & 511;
        float4 v = *(const float4*)(wc_src_row(row, Wq, Wkv) + col);
        ushort4 o = { f2b(v.x), f2b(v.y), f2b(v.z), f2b(v.w) };
        ((ushort4*)Wc_b)[i] = o;
        return;
    }
    i -= NWC4;
    if (i < NWO4) {
        float4 v = ((const float4*)Wo)[i];
        ushort4 o = { f2b(v.x), f2b(v.y), f2b(v.z), f2b(v.w) };
        ((ushort4*)Wo_b)[i] = o;
        return;
    }
    i -= NWO4;
    if (i < NB4) {
#pragma unroll
        for (int u = 0; u < 4; ++u) {
            int r = i * 4 + u;
            float v;
            if (r < 512) v = bq[r];
            else if (r < 1024) { int h = (r - 512) >> 6, j = (r - 512) & 63;  v = bkv[h * 128 + j]; }
            else               { int h = (r - 1024) >> 6, j = (r - 1024) & 63; v = bkv[h * 128 + 64 + j]; }
            bc[r] = v;
        }
    }
}

// ===================== GEMM1: 256^2 tile, 2-phase counted-vmcnt pipeline ====
// T3-minimum (2-phase dbuf): STAGE(T+1) issued BEFORE compute(T); counted
// s_waitcnt vmcnt(8) retires only tile T's 8 ops -> T+1's loads stay in
// flight across the barrier and land under T's ~850cy compute. Raw
// s_barrier (not __syncthreads: that emits vmcnt(0) and drains the
// pipeline - the documented ~20% stall). sched_barrier(0) after each asm
// waitcnt (rule #18). Race audit: end-of-tile barrier separates compute(T)
// from STAGE(T+2)'s overwrite of the same buffer; per-wave ds_reads are
// complete before its barrier (lgkmcnt before MFMA).
// LDS 2x64KB dbuf = 128KB -> 1 block/CU (HK's 8-phase operating point).
__global__ __launch_bounds__(512) void gemm_pipe_k(
    const ushort* __restrict__ Ah, const ushort* __restrict__ Bh,
    const float* __restrict__ bias, ushort* __restrict__ Cout,
    int M, int N, int K, int NCB)
{
    __shared__ ushort lds[2][2 * 16384];   // [dbuf][A(32KB)|B(32KB)] = 128KB
    const int nwg = gridDim.x;
    const int o = blockIdx.x;
    const int q8 = nwg >> 3, r8 = nwg & 7, x = o & 7, sl = o >> 3;
    const int wg = (x < r8 ? x * (q8 + 1) : r8 * (q8 + 1) + (x - r8) * q8) + sl;
    const int row0 = (wg / NCB) * 256, col0 = (wg % NCB) * 256;

    const int tid = threadIdx.x;
    const int wid = tid >> 6, l = tid & 63;
    const int wm = (wid >> 2) * 128, wn = (wid & 3) * 64;
    const int fr = l & 15, g = l >> 4;
    const int fcb = g << 4;

    // stage tile (k0) into buffer bi: 8 global_load_lds ops per thread
    auto STAGE = [&](int bi, int k0) {
#pragma unroll
        for (int p = 0; p < 4; ++p) {
            const int lb  = p * 8192 + tid * 16;            // byte in 32KB tile
            const int r   = lb >> 7;                        // tile row (128B rows)
            const int cbs = (lb & 127) ^ ((r & 7) << 4);    // swizzled source col
            const int ar  = min(row0 + r, M - 1);
            const int br  = col0 + r;                       // N multiple of 256
            const size_t aoff = (size_t)ar * K + k0 + (cbs >> 1);
            const size_t boff = (size_t)br * K + k0 + (cbs >> 1);
            __builtin_amdgcn_global_load_lds(
                (const __attribute__((address_space(1))) void*)(Ah + aoff),
                (__attribute__((address_space(3))) void*)&lds[bi][0 * 16384 + (lb >> 1)], 16, 0, 0);
            __builtin_amdgcn_global_load_lds(
                (const __attribute__((address_space(1))) void*)(Bh + boff),
                (__attribute__((address_space(3))) void*)&lds[bi][1 * 16384 + (lb >> 1)], 16, 0, 0);
        }
    };

    f32x4 acc[8][4] = {};
    const int NTILES = K >> 6;   // 8

    STAGE(0, 0);
    for (int T = 0; T < NTILES; ++T) {
        const int cur = T & 1;
        if (T + 1 < NTILES) {
            STAGE(cur ^ 1, (T + 1) << 6);                  // 8 ops in flight
            asm volatile("s_waitcnt vmcnt(8)" ::: "memory");  // tile T done
        } else {
            asm volatile("s_waitcnt vmcnt(0)" ::: "memory");
        }
        __builtin_amdgcn_sched_barrier(0);
        __builtin_amdgcn_s_barrier();                      // all waves: tile T ready
        __builtin_amdgcn_sched_barrier(0);

#pragma unroll
        for (int kk = 0; kk < 2; ++kk) {
            bf16x8 a[8], b[4];
#pragma unroll
            for (int m = 0; m < 8; ++m) {
                const int r  = wm + m * 16 + fr;
                const int cb = (kk * 64 + fcb) ^ ((r & 7) << 4);
                a[m] = *(const bf16x8*)&lds[cur][0 * 16384 + r * 64 + (cb >> 1)];
            }
#pragma unroll
            for (int n = 0; n < 4; ++n) {
                const int r  = wn + n * 16 + fr;
                const int cb = (kk * 64 + fcb) ^ ((r & 7) << 4);
                b[n] = *(const bf16x8*)&lds[cur][1 * 16384 + r * 64 + (cb >> 1)];
            }
#pragma unroll
            for (int m = 0; m < 8; ++m)
#pragma unroll
                for (int n = 0; n < 4; ++n)
                    acc[m][n] = __builtin_amdgcn_mfma_f32_16x16x32_bf16(a[m], b[n], acc[m][n], 0, 0, 0);
        }

        __builtin_amdgcn_sched_barrier(0);
        __builtin_amdgcn_s_barrier();                      // compute done before next overwrite
    }

    // epilogue: C/D layout col=lane&15, row=(lane>>4)*4+reg  [m89/m91]
#pragma unroll
    for (int n = 0; n < 4; ++n) {
        const int cg = col0 + wn + n * 16 + fr;
        const float bv = bias[cg];
#pragma unroll
        for (int m = 0; m < 8; ++m) {
#pragma unroll
            for (int j = 0; j < 4; ++j) {
                const int rg = row0 + wm + m * 16 + g * 4 + j;
                if (rg < M) Cout[(size_t)rg * N + cg] = f2b(acc[m][n][j] + bv);
            }
        }
    }
}

// ===================== GEMM2: 128^2 tile, r16 structure (control) ===========
__global__ __launch_bounds__(256) void gemm_mfma128(
    const ushort* __restrict__ Ah, const ushort* __restrict__ Bh,
    const float* __restrict__ bias, float* __restrict__ Cout,
    int M, int N, int K, int NCB)
{
    constexpr int LDSH = 128 * 64;
    __shared__ ushort lds[2 * LDSH];
    const int nwg = gridDim.x;
    const int o = blockIdx.x;
    const int q8 = nwg >> 3, r8 = nwg & 7, x = o & 7, sl = o >> 3;
    const int wg = (x < r8 ? x * (q8 + 1) : r8 * (q8 + 1) + (x - r8) * q8) + sl;
    const int row0 = (wg / NCB) * 128, col0 = (wg % NCB) * 128;

    const int tid = threadIdx.x;
    const int wid = tid >> 6, l = tid & 63;
    const int wm = (wid >> 1) * 64, wn = (wid & 1) * 64;
    const int fr = l & 15, g = l >> 4;
    const int fcb = g << 4;

    f32x4 acc[4][4] = {};

    for (int k0 = 0; k0 < K; k0 += 64) {
        __syncthreads();
#pragma unroll
        for (int p = 0; p < 4; ++p) {
            const int lb  = p * 4096 + tid * 16;
            const int r   = lb >> 7;
            const int cbs = (lb & 127) ^ ((r & 7) << 4);
            const int ar  = min(row0 + r, M - 1);
            const int br  = col0 + r;
            const size_t aoff = (size_t)ar * K + k0 + (cbs >> 1);
            const size_t boff = (size_t)br * K + k0 + (cbs >> 1);
            __builtin_amdgcn_global_load_lds(
                (const __attribute__((address_space(1))) void*)(Ah + aoff),
                (__attribute__((address_space(3))) void*)&lds[0 * LDSH + (lb >> 1)], 16, 0, 0);
            __builtin_amdgcn_global_load_lds(
                (const __attribute__((address_space(1))) void*)(Bh + boff),
                (__attribute__((address_space(3))) void*)&lds[1 * LDSH + (lb >> 1)], 16, 0, 0);
        }
        __syncthreads();

#pragma unroll
        for (int kk = 0; kk < 2; ++kk) {
            bf16x8 a[4], b[4];
#pragma unroll
            for (int m = 0; m < 4; ++m) {
                const int r  = wm + m * 16 + fr;
                const int cb = (kk * 64 + fcb) ^ ((r & 7) << 4);
                a[m] = *(const bf16x8*)&lds[0 * LDSH + r * 64 + (cb >> 1)];
            }
#pragma unroll
            for (int n = 0; n < 4; ++n) {
                const int r  = wn + n * 16 + fr;
                const int cb = (kk * 64 + fcb) ^ ((r & 7) << 4);
                b[n] = *(const bf16x8*)&lds[1 * LDSH + r * 64 + (cb >> 1)];
            }
#pragma unroll
            for (int m = 0; m < 4; ++m)
#pragma unroll
                for (int n = 0; n < 4; ++n)
                    acc[m][n] = __builtin_amdgcn_mfma_f32_16x16x32_bf16(a[m], b[n], acc[m][n], 0, 0, 0);
        }
    }

#pragma unroll
    for (int n = 0; n < 4; ++n) {
        const int cg = col0 + wn + n * 16 + fr;
        const float bv = bias[cg];
#pragma unroll
        for (int m = 0; m < 4; ++m) {
#pragma unroll
            for (int j = 0; j < 4; ++j) {
                const int rg = row0 + wm + m * 16 + g * 4 + j;
                if (rg < M) Cout[(size_t)rg * N + cg] = acc[m][n][j] + bv;
            }
        }
    }
}

// ===================== CSR build ============================================
__global__ __launch_bounds__(1024) void scan_counts_k(
    const int* __restrict__ counts, int* __restrict__ indptr,
    int* __restrict__ dbase, int M)
{
    __shared__ int part[1024];
    __shared__ int hist[128];
    const int t  = threadIdx.x;
    if (t < 128) hist[t] = 0;
    __syncthreads();
    const int CH = (M + 1023) / 1024;
    const int base = t * CH;
    int sum = 0;
    for (int i = 0; i < CH; ++i) {
        int idx = base + i;
        if (idx < M) {
            int c = counts[idx];
            sum += c;
            atomicAdd(&hist[127 - min(c, 127)], 1);
        }
    }
    part[t] = sum;
    __syncthreads();
    for (int off = 1; off < 1024; off <<= 1) {
        int v = (t >= off) ? part[t - off] : 0;
        __syncthreads();
        part[t] += v;
        __syncthreads();
    }
    int excl = part[t] - sum;
    for (int i = 0; i < CH; ++i) {
        int idx = base + i;
        if (idx < M) { indptr[idx] = excl; excl += counts[idx]; }
    }
    if (t == 1023) indptr[M] = part[1023];
    if (t == 0) {
        int run = 0;
        for (int b = 0; b < 128; ++b) { int v = hist[b]; dbase[b] = run; run += v; }
    }
}

// per-node: exclusive scan of NT tile counts -> scatter cursors
// (parallel-sized: 79 blocks; r14's 1-block fusion of this cost 412us)
__global__ void tileoff_k(const int* __restrict__ indptr, const int* __restrict__ counts2,
                          int* __restrict__ cursor2, int M)
{
    int n = blockIdx.x * blockDim.x + threadIdx.x;
    if (n >= M) return;
    int run = indptr[n];
#pragma unroll
    for (int j = 0; j < NT; ++j) {
        cursor2[n * NT + j] = run;
        run += counts2[n * NT + j];
    }
}

// fused: edge scatter (tile-sorted byte offsets) + degree-sorted perm scatter
__global__ void scatter_fused_k(const int* __restrict__ src, const int* __restrict__ tgt,
                                int* __restrict__ cursor2, int* __restrict__ slot_off,
                                const int* __restrict__ counts, const int* __restrict__ dbase,
                                int* __restrict__ dcur, int* __restrict__ perm, int E, int M)
{
    int e = blockIdx.x * blockDim.x + threadIdx.x;
    if (e < E) {
        int t = tgt[e], s = src[e];
        int pos = atomicAdd(&cursor2[t * NT + (s >> TSHIFT)], 1);
        slot_off[pos] = s * 3072;
    }
    if (e < M) {
        int b = 127 - min(counts[e], 127);
        int pos = atomicAdd(&dcur[b], 1);
        perm[dbase[b] + pos] = e;
    }
}

// ===================== attention: r6 loop + tile-sorted slot lists ==========
// Model (r6-r13): time = lines x avg_latency / (per-CU MSHR queue x 256CU).
// Tile-sorted sweep cut latency 15%; window size beyond that is drift-limited
// -> parked at ~142us / 497MB FETCH.
__global__ __launch_bounds__(256, 4) void attn11_k(
    const ushort* __restrict__ qkv, const int* __restrict__ indptr,
    const int* __restrict__ slot_off, const int* __restrict__ perm,
    ushort* __restrict__ obh)
{
    __shared__ int slots[4][CAP];
    const int w = threadIdx.x >> 6;
    const int l = threadIdx.x & 63;
    const int node = perm[blockIdx.x * 4 + w];
    const int beg = indptr[node], end = indptr[node + 1];
    const int d = end - beg;
    const int dc = min(d, CAP);

    for (int i = l; i < dc; i += 64) slots[w][i] = slot_off[beg + i];
    __syncthreads();

    const char* base = (const char*)qkv + (l << 4);

    float qf[8];
    {
        bf16x8 qv = *(const bf16x8*)(base + (size_t)node * 3072);
#pragma unroll
        for (int j = 0; j < 8; ++j) qf[j] = b2f((ushort)qv[j]);
    }

    float acc[8] = {};
    float ssum = 0.f;

    int i = 0;
    for (; i + 8 <= dc; i += 8) {
        const int4 sa = *(const int4*)&slots[w][i];
        const int4 sb = *(const int4*)&slots[w][i + 4];
        const char* bp[8] = { base + sa.x, base + sa.y, base + sa.z, base + sa.w,
                              base + sb.x, base + sb.y, base + sb.z, base + sb.w };
        bf16x8 kk[8], vv[8];
#pragma unroll
        for (int u = 0; u < 8; ++u) {
            kk[u] = *(const bf16x8*)(bp[u] + 1024);
            vv[u] = *(const bf16x8*)(bp[u] + 2048);
        }
        float p[8];
#pragma unroll
        for (int u = 0; u < 8; ++u) {
            float pu = 0.f;
#pragma unroll
            for (int j = 0; j < 8; ++j) pu = fmaf(qf[j], b2f((ushort)kk[u][j]), pu);
            p[u] = pu;
        }
#pragma unroll
        for (int u = 0; u < 8; ++u) p[u] += __shfl_xor(p[u], 1);
#pragma unroll
        for (int u = 0; u < 8; ++u) p[u] += __shfl_xor(p[u], 2);
#pragma unroll
        for (int u = 0; u < 8; ++u) p[u] += __shfl_xor(p[u], 4);
        float wt[8];
#pragma unroll
        for (int u = 0; u < 8; ++u) { wt[u] = __expf(p[u] * 0.125f); ssum += wt[u]; }
#pragma unroll
        for (int u = 0; u < 8; ++u)
#pragma unroll
            for (int j = 0; j < 8; ++j) acc[j] = fmaf(wt[u], b2f((ushort)vv[u][j]), acc[j]);
    }
    // tail: remainder of cached region + (astronomically rare) deg>CAP spill
    for (; i < d; ++i) {
        const int so = (i < CAP) ? slots[w][i] : slot_off[beg + i];
        const char* b0 = base + so;
        bf16x8 k0 = *(const bf16x8*)(b0 + 1024);
        bf16x8 v0 = *(const bf16x8*)(b0 + 2048);
        float p0 = 0.f;
#pragma unroll
        for (int j = 0; j < 8; ++j) p0 = fmaf(qf[j], b2f((ushort)k0[j]), p0);
        p0 += __shfl_xor(p0, 1); p0 += __shfl_xor(p0, 2); p0 += __shfl_xor(p0, 4);
        const float w0 = __expf(p0 * 0.125f);
        ssum += w0;
#pragma unroll
        for (int j = 0; j < 8; ++j) acc[j] = fmaf(w0, b2f((ushort)v0[j]), acc[j]);
    }

    // epilogue: normalize + bf16 store
    const float inv = (d > 0) ? 1.f / ssum : 0.f;
    ushort4 ph0, ph1;
    ph0.x = f2b(acc[0] * inv); ph0.y = f2b(acc[1] * inv);
    ph0.z = f2b(acc[2] * inv); ph0.w = f2b(acc[3] * inv);
    ph1.x = f2b(acc[4] * inv); ph1.y = f2b(acc[5] * inv);
    ph1.z = f2b(acc[6] * inv); ph1.w = f2b(acc[7] * inv);
    const size_t ob_off = (size_t)node * 512 + (l << 3);
    *(ushort4*)(obh + ob_off)     = ph0;
    *(ushort4*)(obh + ob_off + 4) = ph1;
}

// ===================== launch ===============================================
extern "C" void kernel_launch(void* const* d_in, const int* in_sizes, int n_in,
                              void* d_out, int out_size, void* d_ws, size_t ws_size,
                              hipStream_t stream)
{
    const float* s   = (const float*)d_in[0];
    const int*   eix = (const int*)d_in[1];   // [2, E]: row0 = src, row1 = tgt
    const float* Wq  = (const float*)d_in[2];
    const float* bq  = (const float*)d_in[3];
    const float* Wkv = (const float*)d_in[4];
    const float* bkv = (const float*)d_in[5];
    const float* Wo  = (const float*)d_in[6];
    const float* bo  = (const float*)d_in[7];
    float* out = (float*)d_out;

    char* ws = (char*)d_ws;
    auto take = [&](size_t bytes) { char* p = ws; ws += (bytes + 255) & ~(size_t)255; return p; };
    ushort* qkv_b  = (ushort*)take((size_t)MN * 1536 * 2);
    ushort* s_b    = (ushort*)take((size_t)MN * 512 * 2);
    ushort* obh    = (ushort*)take((size_t)MN * 512 * 2);
    ushort* Wc_b   = (ushort*)take((size_t)1536 * 512 * 2);
    ushort* Wo_b   = (ushort*)take((size_t)512 * 512 * 2);
    float*  bc     = (float*)take(1536 * 4);
    // contiguous zero-init region: counts | dcur | counts2  (one memset)
    int* counts    = (int*)take(((size_t)MN + 128 + (size_t)MN * NT) * 4);
    int* dcur      = counts + MN;
    int* counts2   = dcur + 128;
    int* cursor2   = (int*)take((size_t)MN * NT * 4);
    int* slot_off  = (int*)take((size_t)NE * 4);
    int* indptr    = (int*)take((MN + 4) * 4);
    int* dbase     = (int*)take(128 * 4);
    int* perm      = (int*)take(MN * 4);

    hipMemsetAsync(counts, 0, ((size_t)MN + 128 + (size_t)MN * NT) * 4, stream);

    // fused conversions / permutations / edge histograms
    const int convN = NS4 + NWC4 + NWO4 + NB4;
    conv_all_k<<<(convN + 255) / 256, 256, 0, stream>>>(s, Wq, Wkv, Wo, bq, bkv,
                                                        eix, eix + NE, counts, counts2,
                                                        s_b, Wc_b, Wo_b, bc);

    // CSR by target (tile-sorted lists) + degree sort
    scan_counts_k<<<1, 1024, 0, stream>>>(counts, indptr, dbase, MN);
    tileoff_k<<<(MN + 255) / 256, 256, 0, stream>>>(indptr, counts2, cursor2, MN);
    scatter_fused_k<<<NE / 256, 256, 0, stream>>>(eix, eix + NE, cursor2, slot_off,
                                                  counts, dbase, dcur, perm, NE, MN);

    // QKV projection: 256^2 2-phase pipelined (474 blocks, 1/CU, dbuf 128KB)
    const int g1 = ((MN + 255) / 256) * (1536 / 256);   // 79 x 6 = 474
    gemm_pipe_k<<<g1, 512, 0, stream>>>(s_b, Wc_b, bc, qkv_b, MN, 1536, DM, 1536 / 256);

    // attention: one wave per node (degree-sorted), tile-sorted gathers
    attn11_k<<<MN / 4, 256, 0, stream>>>(qkv_b, indptr, slot_off, perm, obh);

    // output projection: 128^2 tile (628 blocks; control, unchanged from r16)
    const int g2 = ((MN + 127) / 128) * (512 / 128);    // 157 x 4 = 628
    gemm_mfma128<<<g2, 256, 0, stream>>>(obh, Wo_b, bo, out, MN, 512, DM, 512 / 128);
}